// Round 8
// baseline (245.745 us; speedup 1.0000x reference)
//
#include <hip/hip_runtime.h>
#include <hip/hip_bf16.h>

#define D_MODEL 1024
#define NUM_HEADS 16
#define HEAD_DIM 64
#define SEQ 2048
#define BATCH 2
#define ROWS (BATCH * SEQ)  // 4096

typedef unsigned short u16;
typedef __bf16 bf16x8 __attribute__((ext_vector_type(8)));
typedef float f32x4 __attribute__((ext_vector_type(4)));

__device__ inline u16 f2bfu(float f) {
  // RNE float->bf16
  unsigned u = __float_as_uint(f);
  unsigned r = (u + 0x7fffu + ((u >> 16) & 1u)) >> 16;
  return (u16)r;
}

// packed f32x2 -> bf16x2 (one v_cvt_pk_bf16_f32 on gfx950; RNE fallback otherwise)
__device__ inline unsigned cvt_pk_bf16(float a, float b) {
#if __has_builtin(__builtin_amdgcn_cvt_pk_bf16_f32)
  auto r = __builtin_amdgcn_cvt_pk_bf16_f32(a, b);
  unsigned u;
  __builtin_memcpy(&u, &r, 4);
  return u;
#else
  return (unsigned)f2bfu(a) | ((unsigned)f2bfu(b) << 16);
#endif
}

__device__ inline f32x4 mfma16(bf16x8 a, bf16x8 b, f32x4 c) {
  return __builtin_amdgcn_mfma_f32_16x16x32_bf16(a, b, c, 0, 0, 0);
}

__device__ inline bf16x8 load_frag(const u16* p) {
  union { uint4 v; bf16x8 f; } u;
  u.v = *(const uint4*)p;
  return u.f;
}

// async global->LDS, 16B per lane; LDS dest = wave-uniform base + lane*16
__device__ inline void gload_lds16(const u16* g, u16* l) {
  __builtin_amdgcn_global_load_lds((const __attribute__((address_space(1))) void*)g,
                                   (__attribute__((address_space(3))) void*)l, 16, 0, 0);
}

// ---------------- converters ----------------

__global__ __launch_bounds__(256) void cvt_x_kernel(const float* __restrict__ x,
                                                    u16* __restrict__ y) {
  int i = blockIdx.x * 256 + threadIdx.x;  // each handles 4 floats
  float4 v = ((const float4*)x)[i];
  uint2 o;
  o.x = cvt_pk_bf16(v.x, v.y);
  o.y = cvt_pk_bf16(v.z, v.w);
  ((uint2*)y)[i] = o;
}

// W [K][N] fp32 -> Wt [N][K] bf16
__global__ __launch_bounds__(256) void transpose_cvt(const float* __restrict__ W,
                                                     u16* __restrict__ Wt,
                                                     int K, int N) {
  __shared__ float t[32][33];
  int k0 = blockIdx.x * 32, n0 = blockIdx.y * 32;
  int c = threadIdx.x & 31, r8 = threadIdx.x >> 5;
#pragma unroll
  for (int i = 0; i < 4; i++) {
    int r = r8 + i * 8;
    t[r][c] = W[(size_t)(k0 + r) * N + n0 + c];
  }
  __syncthreads();
#pragma unroll
  for (int i = 0; i < 4; i++) {
    int r = r8 + i * 8;
    Wt[(size_t)(n0 + r) * K + k0 + c] = f2bfu(t[c][r]);
  }
}

// ---------------- GEMM 1: qkv = x @ W_qkv + b -> Qb/Kb [bh][s][64], Vt [bh][d][s] ----------------
// 128(M) x 64(N) tile, BK=64 -> grid 48x32 = 1536 blocks (~5-6/CU resident).
// global_load_lds width=16, fragment-ordered LDS (16-row block = 1024 u16,
// granule kg at kg*128, row at ln*8). Wave w owns rows w*32..w*32+31, all 64 cols.

__global__ __launch_bounds__(256) void gemm_qkv(const u16* __restrict__ A,   // xb [4096][1024]
                                                const u16* __restrict__ Bt,  // WqkvT [3072][1024]
                                                const float* __restrict__ bias,
                                                u16* __restrict__ Qb, u16* __restrict__ Kb,
                                                u16* __restrict__ Vt) {
  __shared__ u16 lA[128 * 64];  // 16 KB
  __shared__ u16 lB[64 * 64];   // 8 KB
  const int tid = threadIdx.x;
  const int wave = tid >> 6, lane = tid & 63, ln = lane & 15, quad = lane >> 4;
  const int n0 = blockIdx.x * 64, m0 = blockIdx.y * 128;
  f32x4 acc[2][4] = {};

  for (int kt = 0; kt < 16; ++kt) {
    const int k0 = kt * 64;
    __syncthreads();
#pragma unroll
    for (int i = 0; i < 6; ++i) {
      int c = wave * 6 + i;  // 24 chunks: 16 A + 8 B (1KB each)
      if (c < 16) {
        int rb = c >> 1, kgh = c & 1;
        gload_lds16(A + (size_t)(m0 + rb * 16 + ln) * 1024 + k0 + (kgh * 4 + quad) * 8,
                    lA + rb * 1024 + kgh * 512);
      } else {
        int cc = c - 16, rb = cc >> 1, kgh = cc & 1;
        gload_lds16(Bt + (size_t)(n0 + rb * 16 + ln) * 1024 + k0 + (kgh * 4 + quad) * 8,
                    lB + rb * 1024 + kgh * 512);
      }
    }
    __syncthreads();
#pragma unroll
    for (int ks = 0; ks < 2; ++ks) {
      bf16x8 a[2], b[4];
#pragma unroll
      for (int i = 0; i < 2; ++i)
        a[i] = load_frag(lA + (wave * 2 + i) * 1024 + (ks * 4 + quad) * 128 + ln * 8);
#pragma unroll
      for (int i = 0; i < 4; ++i)
        b[i] = load_frag(lB + i * 1024 + (ks * 4 + quad) * 128 + ln * 8);
#pragma unroll
      for (int mt = 0; mt < 2; ++mt)
#pragma unroll
        for (int nt = 0; nt < 4; ++nt) acc[mt][nt] = mfma16(a[mt], b[nt], acc[mt][nt]);
    }
  }
#pragma unroll
  for (int mt = 0; mt < 2; ++mt) {
    int row = m0 + wave * 32 + mt * 16 + quad * 4;
    int bb = row >> 11, s0 = row & 2047;
#pragma unroll
    for (int nt = 0; nt < 4; ++nt) {
      int col = n0 + nt * 16 + ln;
      float bv = bias[col];
      int h = col / 192, rem = col - h * 192, t3 = rem >> 6, d = rem & 63;
      int bh = bb * NUM_HEADS + h;
      if (t3 == 2) {  // V -> transposed layout [bh][d][s], 4 consecutive s packed
        uint2 pk;
        pk.x = cvt_pk_bf16(acc[mt][nt][0] + bv, acc[mt][nt][1] + bv);
        pk.y = cvt_pk_bf16(acc[mt][nt][2] + bv, acc[mt][nt][3] + bv);
        *(uint2*)(Vt + ((size_t)bh * 64 + d) * SEQ + s0) = pk;
      } else {
        u16* dst = (t3 == 0) ? Qb : Kb;
#pragma unroll
        for (int r = 0; r < 4; ++r)
          dst[((size_t)bh * SEQ + s0 + r) * 64 + d] = f2bfu(acc[mt][nt][r] + bv);
      }
    }
  }
}

// ---------------- flash attention, balanced-pair blocks ----------------
// Block j (0..15) handles q-tiles lo=j and hi=31-j (64 rows each): total work
// (lo+1)+(hi+1) = 33 key-tiles for EVERY block -> perfect balance.
// 8 waves: waves 0-3 own lo rows (wave&3)*16, waves 4-7 own hi rows.
// Per 64-key tile: stage K (8KB) + Vt (8KB) once via global_load_lds w16 (2 chunks/wave),
// lo-waves predicate off for kt > lo. 2 barriers/tile.
// S^T = K·Q^T (A from lK, B = Q regs); softmax raw-domain (scale folded into exp FMA);
// P via per-wave swizzled LDS (packed cvt); O^T += V^T·P^T (A from lV).

__global__ __launch_bounds__(512) void attn_kernel(const u16* __restrict__ Qb,
                                                   const u16* __restrict__ Kb,
                                                   const u16* __restrict__ Vt,
                                                   u16* __restrict__ Ob) {
  __shared__ u16 lK[64 * 64];   // fragment order, 4 blocks of 16 key-rows
  __shared__ u16 lV[64 * 64];   // fragment order, 4 blocks of 16 d-rows
  __shared__ u16 lP[8][2048];   // per-wave P swizzle + epilogue (16x72 fits)
  const int tid = threadIdx.x;
  const int wave = tid >> 6, lane = tid & 63;
  const int ln = lane & 15, quad = lane >> 4;
  const int j = blockIdx.x;         // 0..15
  const int lo = j, hi = 31 - j;
  const int myt = (wave < 4) ? lo : hi;
  const int q0w = myt * 64 + (wave & 3) * 16;  // this wave's 16-row base
  const int ktend = myt;
  const int bh = blockIdx.y;
  const u16* Qg = Qb + (size_t)bh * SEQ * 64;
  const u16* Kg = Kb + (size_t)bh * SEQ * 64;
  const u16* Vg = Vt + (size_t)bh * 64 * SEQ;
  u16* lPw = lP[wave];

  // staging pointers, hoisted: wave w stages chunks c = w*2, w*2+1 (c<8 -> K, else V)
  const u16* sp[2];
  u16* dp[2];
  const int sstride = (wave < 4) ? 64 * 64 : 64;  // K: +64 rows; V: +64 cols
#pragma unroll
  for (int i = 0; i < 2; ++i) {
    int c = wave * 2 + i;
    if (c < 8) {
      int rb = c >> 1, kgh = c & 1;
      sp[i] = Kg + (size_t)(rb * 16 + ln) * 64 + (kgh * 4 + quad) * 8;
      dp[i] = lK + rb * 1024 + kgh * 512;
    } else {
      int cc = c - 8, rb = cc >> 1, kgh = cc & 1;
      sp[i] = Vg + (size_t)(rb * 16 + ln) * SEQ + (kgh * 4 + quad) * 8;
      dp[i] = lV + rb * 1024 + kgh * 512;
    }
  }

  // Q B-frags, loaded once: qf[ks] = Q[q0w+ln][ks*32+quad*8 ..+8]
  bf16x8 qf[2];
#pragma unroll
  for (int ks = 0; ks < 2; ++ks)
    qf[ks] = load_frag(Qg + (size_t)(q0w + ln) * 64 + ks * 32 + quad * 8);

  f32x4 o[4] = {};     // O^T: row d=dt*16+quad*4+r, col q=ln (this wave's 16 q)
  float m_r = -1e30f;  // raw-score domain
  float l_r = 0.f;
  const float SC = 0.18033688011112042f;  // log2(e) / sqrt(64)
  const int qq = q0w + ln;

  for (int kt = 0; kt <= hi; ++kt) {
    __syncthreads();  // previous tile fully consumed
#pragma unroll
    for (int i = 0; i < 2; ++i) gload_lds16(sp[i], dp[i]);
#pragma unroll
    for (int i = 0; i < 2; ++i) sp[i] += sstride;
    __syncthreads();  // staging complete

    if (kt <= ktend) {
      // S^T tile: 64 keys x 16 q
      f32x4 sc[4] = {};
#pragma unroll
      for (int mt = 0; mt < 4; ++mt) {
#pragma unroll
        for (int ks = 0; ks < 2; ++ks) {
          bf16x8 kf = load_frag(lK + mt * 1024 + (ks * 4 + quad) * 128 + ln * 8);
          sc[mt] = mfma16(kf, qf[ks], sc[mt]);
        }
      }
      // causal mask (raw domain), only possible on this wave's diagonal tile
      if (kt == ktend) {
#pragma unroll
        for (int mt = 0; mt < 4; ++mt) {
          int key0 = kt * 64 + mt * 16 + quad * 4;
#pragma unroll
          for (int r = 0; r < 4; ++r)
            if (key0 + r > qq) sc[mt][r] = -1e30f;
        }
      }
      // online softmax: 16 in-lane values + butterfly over quads (lanes ^16, ^32)
      float mloc = sc[0][0];
#pragma unroll
      for (int mt = 0; mt < 4; ++mt)
#pragma unroll
        for (int r = 0; r < 4; ++r) mloc = fmaxf(mloc, sc[mt][r]);
      mloc = fmaxf(mloc, __shfl_xor(mloc, 16));
      mloc = fmaxf(mloc, __shfl_xor(mloc, 32));
      float mnew = fmaxf(m_r, mloc);
      float alpha = __builtin_amdgcn_exp2f((m_r - mnew) * SC);
      float nmsc = -mnew * SC;
      float sum = 0.f;
#pragma unroll
      for (int mt = 0; mt < 4; ++mt)
#pragma unroll
        for (int r = 0; r < 4; ++r) {
          float p = __builtin_amdgcn_exp2f(__builtin_fmaf(sc[mt][r], SC, nmsc));
          sc[mt][r] = p;
          sum += p;
        }
      sum += __shfl_xor(sum, 16);
      sum += __shfl_xor(sum, 32);
      l_r = l_r * alpha + sum;
      m_r = mnew;
#pragma unroll
      for (int dt = 0; dt < 4; ++dt) o[dt] *= alpha;

      // P -> per-wave LDS, [q][k] with k-granule XOR swizzle, packed b64 writes
#pragma unroll
      for (int mt = 0; mt < 4; ++mt) {
        uint2 pk;
        pk.x = cvt_pk_bf16(sc[mt][0], sc[mt][1]);
        pk.y = cvt_pk_bf16(sc[mt][2], sc[mt][3]);
        int addr = ln * 64 + (((mt * 2 + (quad >> 1)) ^ (ln & 7)) * 8) + (quad & 1) * 4;
        *(uint2*)(lPw + addr) = pk;
      }
      bf16x8 pf[2];
#pragma unroll
      for (int ks = 0; ks < 2; ++ks)
        pf[ks] = load_frag(lPw + ln * 64 + (((ks * 4 + quad) ^ (ln & 7)) * 8));
      // O^T += V^T · P^T
#pragma unroll
      for (int dt = 0; dt < 4; ++dt) {
#pragma unroll
        for (int ks = 0; ks < 2; ++ks) {
          bf16x8 av = load_frag(lV + dt * 1024 + (ks * 4 + quad) * 128 + ln * 8);
          o[dt] = mfma16(av, pf[ks], o[dt]);
        }
      }
    }
  }

  // epilogue: normalize, transpose O^T -> [q][d] via wave-private LDS, 16B stores
  float inv = 1.f / l_r;
#pragma unroll
  for (int dt = 0; dt < 4; ++dt) {
    uint2 pk;
    pk.x = cvt_pk_bf16(o[dt][0] * inv, o[dt][1] * inv);
    pk.y = cvt_pk_bf16(o[dt][2] * inv, o[dt][3] * inv);
    *(uint2*)(lPw + ln * 72 + dt * 16 + quad * 4) = pk;
  }
  const int b = bh >> 4, h = bh & 15;
#pragma unroll
  for (int i = 0; i < 2; ++i) {
    int c = lane + i * 64;
    int qq2 = c >> 3, dg = c & 7;
    uint4 val = *(const uint4*)(lPw + qq2 * 72 + dg * 8);
    *(uint4*)(Ob + ((size_t)b * SEQ + q0w + qq2) * 1024 + h * 64 + dg * 8) = val;
  }
}

// ---------------- GEMM 2: out = values @ W_out + b (fp32 out) ----------------
// 64(M) x 64(N) tiles -> grid 16x64 = 1024 blocks (4/CU), BK=64, LDS 16 KB.

__global__ __launch_bounds__(256) void gemm_out(const u16* __restrict__ A,   // Ob [4096][1024]
                                                const u16* __restrict__ Bt,  // WoutT [1024][1024]
                                                const float* __restrict__ bias,
                                                float* __restrict__ out) {
  __shared__ u16 lA[64 * 64];
  __shared__ u16 lB[64 * 64];
  const int tid = threadIdx.x;
  const int wave = tid >> 6, lane = tid & 63, ln = lane & 15, quad = lane >> 4;
  const int n0 = blockIdx.x * 64, m0 = blockIdx.y * 64;
  const int wm = (wave & 1) * 32, wn = (wave >> 1) * 32;
  f32x4 acc[2][2] = {};

  for (int kt = 0; kt < 16; ++kt) {
    const int k0 = kt * 64;
    __syncthreads();
#pragma unroll
    for (int i = 0; i < 4; ++i) {
      int c = wave * 4 + i;  // 16 chunks: 8 A + 8 B
      if (c < 8) {
        int rb = c >> 1, kgh = c & 1;
        gload_lds16(A + (size_t)(m0 + rb * 16 + ln) * 1024 + k0 + (kgh * 4 + quad) * 8,
                    lA + rb * 1024 + kgh * 512);
      } else {
        int cc = c - 8, rb = cc >> 1, kgh = cc & 1;
        gload_lds16(Bt + (size_t)(n0 + rb * 16 + ln) * 1024 + k0 + (kgh * 4 + quad) * 8,
                    lB + rb * 1024 + kgh * 512);
      }
    }
    __syncthreads();
#pragma unroll
    for (int ks = 0; ks < 2; ++ks) {
      bf16x8 a[2], b[2];
#pragma unroll
      for (int i = 0; i < 2; ++i) {
        a[i] = load_frag(lA + (wm / 16 + i) * 1024 + (ks * 4 + quad) * 128 + ln * 8);
        b[i] = load_frag(lB + (wn / 16 + i) * 1024 + (ks * 4 + quad) * 128 + ln * 8);
      }
#pragma unroll
      for (int mt = 0; mt < 2; ++mt)
#pragma unroll
        for (int nt = 0; nt < 2; ++nt) acc[mt][nt] = mfma16(a[mt], b[nt], acc[mt][nt]);
    }
  }
#pragma unroll
  for (int mt = 0; mt < 2; ++mt) {
    int row = m0 + wm + mt * 16 + quad * 4;
#pragma unroll
    for (int nt = 0; nt < 2; ++nt) {
      int col = n0 + wn + nt * 16 + ln;
      float bv = bias[col];
#pragma unroll
      for (int r = 0; r < 4; ++r)
        out[(size_t)(row + r) * 1024 + col] = acc[mt][nt][r] + bv;
    }
  }
}

// ---------------- launcher ----------------

extern "C" void kernel_launch(void* const* d_in, const int* in_sizes, int n_in,
                              void* d_out, int out_size, void* d_ws, size_t ws_size,
                              hipStream_t stream) {
  const float* x = (const float*)d_in[0];
  const float* W_qkv = (const float*)d_in[1];
  const float* b_qkv = (const float*)d_in[2];
  const float* W_out = (const float*)d_in[3];
  const float* b_out = (const float*)d_in[4];
  float* out = (float*)d_out;

  char* ws = (char*)d_ws;
  const size_t SZ_XB = (size_t)ROWS * D_MODEL * 2;            // 8 MiB
  const size_t SZ_WQKVT = (size_t)3 * D_MODEL * D_MODEL * 2;  // 6 MiB
  const size_t SZ_WOUTT = (size_t)D_MODEL * D_MODEL * 2;      // 2 MiB
  const size_t SZ_HEADS = (size_t)BATCH * NUM_HEADS * SEQ * HEAD_DIM * 2;  // 8 MiB
  u16* xb = (u16*)(ws);
  u16* WqkvT = (u16*)(ws + SZ_XB);
  u16* WoutT = (u16*)(ws + SZ_XB + SZ_WQKVT);
  u16* Qb = (u16*)(ws + SZ_XB + SZ_WQKVT + SZ_WOUTT);
  u16* Kb = (u16*)(ws + SZ_XB + SZ_WQKVT + SZ_WOUTT + SZ_HEADS);
  u16* Vt = (u16*)(ws + SZ_XB + SZ_WQKVT + SZ_WOUTT + 2 * SZ_HEADS);
  u16* Ob = (u16*)(ws + SZ_XB + SZ_WQKVT + SZ_WOUTT + 3 * SZ_HEADS);

  cvt_x_kernel<<<dim3(ROWS * D_MODEL / 4 / 256), dim3(256), 0, stream>>>(x, xb);
  transpose_cvt<<<dim3(D_MODEL / 32, 3 * D_MODEL / 32), dim3(256), 0, stream>>>(W_qkv, WqkvT,
                                                                                D_MODEL, 3 * D_MODEL);
  transpose_cvt<<<dim3(D_MODEL / 32, D_MODEL / 32), dim3(256), 0, stream>>>(W_out, WoutT,
                                                                            D_MODEL, D_MODEL);
  gemm_qkv<<<dim3(3 * D_MODEL / 64, ROWS / 128), dim3(256), 0, stream>>>(xb, WqkvT, b_qkv,
                                                                         Qb, Kb, Vt);
  attn_kernel<<<dim3(SEQ / 128, BATCH * NUM_HEADS), dim3(512), 0, stream>>>(Qb, Kb, Vt, Ob);
  gemm_out<<<dim3(D_MODEL / 64, ROWS / 64), dim3(256), 0, stream>>>(Ob, WoutT, b_out, out);
}

// Round 9
// 228.721 us; speedup vs baseline: 1.0744x; 1.0744x over previous
//
#include <hip/hip_runtime.h>
#include <hip/hip_bf16.h>

#define D_MODEL 1024
#define NUM_HEADS 16
#define HEAD_DIM 64
#define SEQ 2048
#define BATCH 2
#define ROWS (BATCH * SEQ)  // 4096

typedef unsigned short u16;
typedef __bf16 bf16x8 __attribute__((ext_vector_type(8)));
typedef float f32x4 __attribute__((ext_vector_type(4)));

__device__ inline u16 f2bfu(float f) {
  // RNE float->bf16
  unsigned u = __float_as_uint(f);
  unsigned r = (u + 0x7fffu + ((u >> 16) & 1u)) >> 16;
  return (u16)r;
}

// packed f32x2 -> bf16x2 (one v_cvt_pk_bf16_f32 on gfx950; RNE fallback otherwise)
__device__ inline unsigned cvt_pk_bf16(float a, float b) {
#if __has_builtin(__builtin_amdgcn_cvt_pk_bf16_f32)
  auto r = __builtin_amdgcn_cvt_pk_bf16_f32(a, b);
  unsigned u;
  __builtin_memcpy(&u, &r, 4);
  return u;
#else
  return (unsigned)f2bfu(a) | ((unsigned)f2bfu(b) << 16);
#endif
}

__device__ inline f32x4 mfma16(bf16x8 a, bf16x8 b, f32x4 c) {
  return __builtin_amdgcn_mfma_f32_16x16x32_bf16(a, b, c, 0, 0, 0);
}

__device__ inline bf16x8 load_frag(const u16* p) {
  union { uint4 v; bf16x8 f; } u;
  u.v = *(const uint4*)p;
  return u.f;
}

// async global->LDS, 16B per lane; LDS dest = wave-uniform base + lane*16
__device__ inline void gload_lds16(const u16* g, u16* l) {
  __builtin_amdgcn_global_load_lds((const __attribute__((address_space(1))) void*)g,
                                   (__attribute__((address_space(3))) void*)l, 16, 0, 0);
}

// ---------------- converters ----------------

__global__ __launch_bounds__(256) void cvt_x_kernel(const float* __restrict__ x,
                                                    u16* __restrict__ y) {
  int i = blockIdx.x * 256 + threadIdx.x;  // each handles 4 floats
  float4 v = ((const float4*)x)[i];
  uint2 o;
  o.x = cvt_pk_bf16(v.x, v.y);
  o.y = cvt_pk_bf16(v.z, v.w);
  ((uint2*)y)[i] = o;
}

// W [K][N] fp32 -> Wt [N][K] bf16
__global__ __launch_bounds__(256) void transpose_cvt(const float* __restrict__ W,
                                                     u16* __restrict__ Wt,
                                                     int K, int N) {
  __shared__ float t[32][33];
  int k0 = blockIdx.x * 32, n0 = blockIdx.y * 32;
  int c = threadIdx.x & 31, r8 = threadIdx.x >> 5;
#pragma unroll
  for (int i = 0; i < 4; i++) {
    int r = r8 + i * 8;
    t[r][c] = W[(size_t)(k0 + r) * N + n0 + c];
  }
  __syncthreads();
#pragma unroll
  for (int i = 0; i < 4; i++) {
    int r = r8 + i * 8;
    Wt[(size_t)(n0 + r) * K + k0 + c] = f2bfu(t[c][r]);
  }
}

// ---------------- GEMM 1: qkv = x @ W_qkv + b -> Qb/Kb [bh][s][64], Vt [bh][d][s] ----------------
// 128x128 tile, BK=32, explicit double buffer with raw s_barrier + s_waitcnt vmcnt(4):
// loads for tile k+1 stay IN FLIGHT across tile k's compute (no vmcnt(0) drain).
// Distinct static LDS arrays per buffer so alias analysis can't force a drain.
// Fragment LDS layout (BK=32): 16-row block = 512 u16; granule quad at quad*128, row at ln*8.

__global__ __launch_bounds__(256, 3) void gemm_qkv(const u16* __restrict__ A,   // xb [4096][1024]
                                                   const u16* __restrict__ Bt,  // WqkvT [3072][1024]
                                                   const float* __restrict__ bias,
                                                   u16* __restrict__ Qb, u16* __restrict__ Kb,
                                                   u16* __restrict__ Vt) {
  __shared__ u16 lA0[128 * 32], lB0[128 * 32];  // 8 KB each
  __shared__ u16 lA1[128 * 32], lB1[128 * 32];
  const int tid = threadIdx.x;
  const int wave = tid >> 6, lane = tid & 63, ln = lane & 15, quad = lane >> 4;
  const int n0 = blockIdx.x * 128, m0 = blockIdx.y * 128;
  const int wm = (wave & 1) * 64, wn = (wave >> 1) * 64;
  f32x4 acc[4][4] = {};

  // per-wave staging: 4 chunks of 1KB (2 A row-blocks + 2 B row-blocks)
  auto issue = [&](u16* dA, u16* dB, int k0) {
#pragma unroll
    for (int i = 0; i < 2; ++i) {
      int rb = wave * 2 + i;  // 0..7
      gload_lds16(A + (size_t)(m0 + rb * 16 + ln) * 1024 + k0 + quad * 8, dA + rb * 512);
      gload_lds16(Bt + (size_t)(n0 + rb * 16 + ln) * 1024 + k0 + quad * 8, dB + rb * 512);
    }
  };
  auto compute = [&](const u16* sA, const u16* sB) {
    bf16x8 a[4], b[4];
#pragma unroll
    for (int i = 0; i < 4; ++i) {
      a[i] = load_frag(sA + (wm / 16 + i) * 512 + quad * 128 + ln * 8);
      b[i] = load_frag(sB + (wn / 16 + i) * 512 + quad * 128 + ln * 8);
    }
#pragma unroll
    for (int mt = 0; mt < 4; ++mt)
#pragma unroll
      for (int nt = 0; nt < 4; ++nt) acc[mt][nt] = mfma16(a[mt], b[nt], acc[mt][nt]);
  };

  issue(lA0, lB0, 0);  // prologue: tile 0 -> buf0
  for (int p = 0; p < 15; ++p) {
    // phase A: computes kt=2p (buf0), issues kt=2p+1 (buf1)
    asm volatile("s_barrier" ::: "memory");  // buf1 consumers of prev phase done
    issue(lA1, lB1, (2 * p + 1) * 32);
    asm volatile("s_waitcnt vmcnt(4)" ::: "memory");  // buf0 (issued last phase) landed
    asm volatile("s_barrier" ::: "memory");
    compute(lA0, lB0);
    // phase B: computes kt=2p+1 (buf1), issues kt=2p+2 (buf0)
    asm volatile("s_barrier" ::: "memory");
    issue(lA0, lB0, (2 * p + 2) * 32);
    asm volatile("s_waitcnt vmcnt(4)" ::: "memory");
    asm volatile("s_barrier" ::: "memory");
    compute(lA1, lB1);
  }
  // p=15 phase A: computes kt=30, issues kt=31
  asm volatile("s_barrier" ::: "memory");
  issue(lA1, lB1, 31 * 32);
  asm volatile("s_waitcnt vmcnt(4)" ::: "memory");
  asm volatile("s_barrier" ::: "memory");
  compute(lA0, lB0);
  // final: compute kt=31
  asm volatile("s_waitcnt vmcnt(0)" ::: "memory");
  asm volatile("s_barrier" ::: "memory");
  compute(lA1, lB1);

#pragma unroll
  for (int mt = 0; mt < 4; ++mt) {
    int row = m0 + wm + mt * 16 + quad * 4;
    int bb = row >> 11, s0 = row & 2047;
#pragma unroll
    for (int nt = 0; nt < 4; ++nt) {
      int col = n0 + wn + nt * 16 + ln;
      float bv = bias[col];
      int h = col / 192, rem = col - h * 192, t3 = rem >> 6, d = rem & 63;
      int bh = bb * NUM_HEADS + h;
      if (t3 == 2) {  // V -> transposed layout [bh][d][s], 4 consecutive s packed
        uint2 pk;
        pk.x = cvt_pk_bf16(acc[mt][nt][0] + bv, acc[mt][nt][1] + bv);
        pk.y = cvt_pk_bf16(acc[mt][nt][2] + bv, acc[mt][nt][3] + bv);
        *(uint2*)(Vt + ((size_t)bh * 64 + d) * SEQ + s0) = pk;
      } else {
        u16* dst = (t3 == 0) ? Qb : Kb;
#pragma unroll
        for (int r = 0; r < 4; ++r)
          dst[((size_t)bh * SEQ + s0 + r) * 64 + d] = f2bfu(acc[mt][nt][r] + bv);
      }
    }
  }
}

// ---------------- flash attention, balanced-pair blocks ----------------
// Block j (0..15) handles q-tiles lo=j and hi=31-j (64 rows each): total work
// (lo+1)+(hi+1) = 33 key-tiles for EVERY block -> perfect balance.
// 8 waves: waves 0-3 own lo rows (wave&3)*16, waves 4-7 own hi rows.
// Per 64-key tile: stage K (8KB) + Vt (8KB) once via global_load_lds w16 (2 chunks/wave),
// lo-waves predicate off for kt > lo. 2 barriers/tile.
// S^T = K·Q^T (A from lK, B = Q regs); softmax raw-domain (scale folded into exp FMA);
// P via per-wave swizzled LDS (packed cvt); O^T += V^T·P^T (A from lV).

__global__ __launch_bounds__(512) void attn_kernel(const u16* __restrict__ Qb,
                                                   const u16* __restrict__ Kb,
                                                   const u16* __restrict__ Vt,
                                                   u16* __restrict__ Ob) {
  __shared__ u16 lK[64 * 64];   // fragment order, 4 blocks of 16 key-rows
  __shared__ u16 lV[64 * 64];   // fragment order, 4 blocks of 16 d-rows
  __shared__ u16 lP[8][2048];   // per-wave P swizzle + epilogue (16x72 fits)
  const int tid = threadIdx.x;
  const int wave = tid >> 6, lane = tid & 63;
  const int ln = lane & 15, quad = lane >> 4;
  const int j = blockIdx.x;         // 0..15
  const int lo = j, hi = 31 - j;
  const int myt = (wave < 4) ? lo : hi;
  const int q0w = myt * 64 + (wave & 3) * 16;  // this wave's 16-row base
  const int ktend = myt;
  const int bh = blockIdx.y;
  const u16* Qg = Qb + (size_t)bh * SEQ * 64;
  const u16* Kg = Kb + (size_t)bh * SEQ * 64;
  const u16* Vg = Vt + (size_t)bh * 64 * SEQ;
  u16* lPw = lP[wave];

  // staging pointers, hoisted: wave w stages chunks c = w*2, w*2+1 (c<8 -> K, else V)
  const u16* sp[2];
  u16* dp[2];
  const int sstride = (wave < 4) ? 64 * 64 : 64;  // K: +64 rows; V: +64 cols
#pragma unroll
  for (int i = 0; i < 2; ++i) {
    int c = wave * 2 + i;
    if (c < 8) {
      int rb = c >> 1, kgh = c & 1;
      sp[i] = Kg + (size_t)(rb * 16 + ln) * 64 + (kgh * 4 + quad) * 8;
      dp[i] = lK + rb * 1024 + kgh * 512;
    } else {
      int cc = c - 8, rb = cc >> 1, kgh = cc & 1;
      sp[i] = Vg + (size_t)(rb * 16 + ln) * SEQ + (kgh * 4 + quad) * 8;
      dp[i] = lV + rb * 1024 + kgh * 512;
    }
  }

  // Q B-frags, loaded once: qf[ks] = Q[q0w+ln][ks*32+quad*8 ..+8]
  bf16x8 qf[2];
#pragma unroll
  for (int ks = 0; ks < 2; ++ks)
    qf[ks] = load_frag(Qg + (size_t)(q0w + ln) * 64 + ks * 32 + quad * 8);

  f32x4 o[4] = {};     // O^T: row d=dt*16+quad*4+r, col q=ln (this wave's 16 q)
  float m_r = -1e30f;  // raw-score domain
  float l_r = 0.f;
  const float SC = 0.18033688011112042f;  // log2(e) / sqrt(64)
  const int qq = q0w + ln;

  for (int kt = 0; kt <= hi; ++kt) {
    __syncthreads();  // previous tile fully consumed
#pragma unroll
    for (int i = 0; i < 2; ++i) gload_lds16(sp[i], dp[i]);
#pragma unroll
    for (int i = 0; i < 2; ++i) sp[i] += sstride;
    __syncthreads();  // staging complete

    if (kt <= ktend) {
      // S^T tile: 64 keys x 16 q
      f32x4 sc[4] = {};
#pragma unroll
      for (int mt = 0; mt < 4; ++mt) {
#pragma unroll
        for (int ks = 0; ks < 2; ++ks) {
          bf16x8 kf = load_frag(lK + mt * 1024 + (ks * 4 + quad) * 128 + ln * 8);
          sc[mt] = mfma16(kf, qf[ks], sc[mt]);
        }
      }
      // causal mask (raw domain), only possible on this wave's diagonal tile
      if (kt == ktend) {
#pragma unroll
        for (int mt = 0; mt < 4; ++mt) {
          int key0 = kt * 64 + mt * 16 + quad * 4;
#pragma unroll
          for (int r = 0; r < 4; ++r)
            if (key0 + r > qq) sc[mt][r] = -1e30f;
        }
      }
      // online softmax: 16 in-lane values + butterfly over quads (lanes ^16, ^32)
      float mloc = sc[0][0];
#pragma unroll
      for (int mt = 0; mt < 4; ++mt)
#pragma unroll
        for (int r = 0; r < 4; ++r) mloc = fmaxf(mloc, sc[mt][r]);
      mloc = fmaxf(mloc, __shfl_xor(mloc, 16));
      mloc = fmaxf(mloc, __shfl_xor(mloc, 32));
      float mnew = fmaxf(m_r, mloc);
      float alpha = __builtin_amdgcn_exp2f((m_r - mnew) * SC);
      float nmsc = -mnew * SC;
      float sum = 0.f;
#pragma unroll
      for (int mt = 0; mt < 4; ++mt)
#pragma unroll
        for (int r = 0; r < 4; ++r) {
          float p = __builtin_amdgcn_exp2f(__builtin_fmaf(sc[mt][r], SC, nmsc));
          sc[mt][r] = p;
          sum += p;
        }
      sum += __shfl_xor(sum, 16);
      sum += __shfl_xor(sum, 32);
      l_r = l_r * alpha + sum;
      m_r = mnew;
#pragma unroll
      for (int dt = 0; dt < 4; ++dt) o[dt] *= alpha;

      // P -> per-wave LDS, [q][k] with k-granule XOR swizzle, packed b64 writes
#pragma unroll
      for (int mt = 0; mt < 4; ++mt) {
        uint2 pk;
        pk.x = cvt_pk_bf16(sc[mt][0], sc[mt][1]);
        pk.y = cvt_pk_bf16(sc[mt][2], sc[mt][3]);
        int addr = ln * 64 + (((mt * 2 + (quad >> 1)) ^ (ln & 7)) * 8) + (quad & 1) * 4;
        *(uint2*)(lPw + addr) = pk;
      }
      bf16x8 pf[2];
#pragma unroll
      for (int ks = 0; ks < 2; ++ks)
        pf[ks] = load_frag(lPw + ln * 64 + (((ks * 4 + quad) ^ (ln & 7)) * 8));
      // O^T += V^T · P^T
#pragma unroll
      for (int dt = 0; dt < 4; ++dt) {
#pragma unroll
        for (int ks = 0; ks < 2; ++ks) {
          bf16x8 av = load_frag(lV + dt * 1024 + (ks * 4 + quad) * 128 + ln * 8);
          o[dt] = mfma16(av, pf[ks], o[dt]);
        }
      }
    }
  }

  // epilogue: normalize, transpose O^T -> [q][d] via wave-private LDS, 16B stores
  float inv = 1.f / l_r;
#pragma unroll
  for (int dt = 0; dt < 4; ++dt) {
    uint2 pk;
    pk.x = cvt_pk_bf16(o[dt][0] * inv, o[dt][1] * inv);
    pk.y = cvt_pk_bf16(o[dt][2] * inv, o[dt][3] * inv);
    *(uint2*)(lPw + ln * 72 + dt * 16 + quad * 4) = pk;
  }
  const int b = bh >> 4, h = bh & 15;
#pragma unroll
  for (int i = 0; i < 2; ++i) {
    int c = lane + i * 64;
    int qq2 = c >> 3, dg = c & 7;
    uint4 val = *(const uint4*)(lPw + qq2 * 72 + dg * 8);
    *(uint4*)(Ob + ((size_t)b * SEQ + q0w + qq2) * 1024 + h * 64 + dg * 8) = val;
  }
}

// ---------------- GEMM 2: out = values @ W_out + b (fp32 out) ----------------
// 64(M) x 64(N) tiles -> grid 16x64 = 1024 blocks (4/CU), BK=64, LDS 16 KB.

__global__ __launch_bounds__(256) void gemm_out(const u16* __restrict__ A,   // Ob [4096][1024]
                                                const u16* __restrict__ Bt,  // WoutT [1024][1024]
                                                const float* __restrict__ bias,
                                                float* __restrict__ out) {
  __shared__ u16 lA[64 * 64];
  __shared__ u16 lB[64 * 64];
  const int tid = threadIdx.x;
  const int wave = tid >> 6, lane = tid & 63, ln = lane & 15, quad = lane >> 4;
  const int n0 = blockIdx.x * 64, m0 = blockIdx.y * 64;
  const int wm = (wave & 1) * 32, wn = (wave >> 1) * 32;
  f32x4 acc[2][2] = {};

  for (int kt = 0; kt < 16; ++kt) {
    const int k0 = kt * 64;
    __syncthreads();
#pragma unroll
    for (int i = 0; i < 4; ++i) {
      int c = wave * 4 + i;  // 16 chunks: 8 A + 8 B
      if (c < 8) {
        int rb = c >> 1, kgh = c & 1;
        gload_lds16(A + (size_t)(m0 + rb * 16 + ln) * 1024 + k0 + (kgh * 4 + quad) * 8,
                    lA + rb * 1024 + kgh * 512);
      } else {
        int cc = c - 8, rb = cc >> 1, kgh = cc & 1;
        gload_lds16(Bt + (size_t)(n0 + rb * 16 + ln) * 1024 + k0 + (kgh * 4 + quad) * 8,
                    lB + rb * 1024 + kgh * 512);
      }
    }
    __syncthreads();
#pragma unroll
    for (int ks = 0; ks < 2; ++ks) {
      bf16x8 a[2], b[2];
#pragma unroll
      for (int i = 0; i < 2; ++i) {
        a[i] = load_frag(lA + (wm / 16 + i) * 1024 + (ks * 4 + quad) * 128 + ln * 8);
        b[i] = load_frag(lB + (wn / 16 + i) * 1024 + (ks * 4 + quad) * 128 + ln * 8);
      }
#pragma unroll
      for (int mt = 0; mt < 2; ++mt)
#pragma unroll
        for (int nt = 0; nt < 2; ++nt) acc[mt][nt] = mfma16(a[mt], b[nt], acc[mt][nt]);
    }
  }
#pragma unroll
  for (int mt = 0; mt < 2; ++mt) {
    int row = m0 + wm + mt * 16 + quad * 4;
#pragma unroll
    for (int nt = 0; nt < 2; ++nt) {
      int col = n0 + wn + nt * 16 + ln;
      float bv = bias[col];
#pragma unroll
      for (int r = 0; r < 4; ++r)
        out[(size_t)(row + r) * 1024 + col] = acc[mt][nt][r] + bv;
    }
  }
}

// ---------------- launcher ----------------

extern "C" void kernel_launch(void* const* d_in, const int* in_sizes, int n_in,
                              void* d_out, int out_size, void* d_ws, size_t ws_size,
                              hipStream_t stream) {
  const float* x = (const float*)d_in[0];
  const float* W_qkv = (const float*)d_in[1];
  const float* b_qkv = (const float*)d_in[2];
  const float* W_out = (const float*)d_in[3];
  const float* b_out = (const float*)d_in[4];
  float* out = (float*)d_out;

  char* ws = (char*)d_ws;
  const size_t SZ_XB = (size_t)ROWS * D_MODEL * 2;            // 8 MiB
  const size_t SZ_WQKVT = (size_t)3 * D_MODEL * D_MODEL * 2;  // 6 MiB
  const size_t SZ_WOUTT = (size_t)D_MODEL * D_MODEL * 2;      // 2 MiB
  const size_t SZ_HEADS = (size_t)BATCH * NUM_HEADS * SEQ * HEAD_DIM * 2;  // 8 MiB
  u16* xb = (u16*)(ws);
  u16* WqkvT = (u16*)(ws + SZ_XB);
  u16* WoutT = (u16*)(ws + SZ_XB + SZ_WQKVT);
  u16* Qb = (u16*)(ws + SZ_XB + SZ_WQKVT + SZ_WOUTT);
  u16* Kb = (u16*)(ws + SZ_XB + SZ_WQKVT + SZ_WOUTT + SZ_HEADS);
  u16* Vt = (u16*)(ws + SZ_XB + SZ_WQKVT + SZ_WOUTT + 2 * SZ_HEADS);
  u16* Ob = (u16*)(ws + SZ_XB + SZ_WQKVT + SZ_WOUTT + 3 * SZ_HEADS);

  cvt_x_kernel<<<dim3(ROWS * D_MODEL / 4 / 256), dim3(256), 0, stream>>>(x, xb);
  transpose_cvt<<<dim3(D_MODEL / 32, 3 * D_MODEL / 32), dim3(256), 0, stream>>>(W_qkv, WqkvT,
                                                                                D_MODEL, 3 * D_MODEL);
  transpose_cvt<<<dim3(D_MODEL / 32, D_MODEL / 32), dim3(256), 0, stream>>>(W_out, WoutT,
                                                                            D_MODEL, D_MODEL);
  gemm_qkv<<<dim3(3 * D_MODEL / 128, ROWS / 128), dim3(256), 0, stream>>>(xb, WqkvT, b_qkv,
                                                                          Qb, Kb, Vt);
  attn_kernel<<<dim3(SEQ / 128, BATCH * NUM_HEADS), dim3(512), 0, stream>>>(Qb, Kb, Vt, Ob);
  gemm_out<<<dim3(D_MODEL / 64, ROWS / 64), dim3(256), 0, stream>>>(Ob, WoutT, b_out, out);
}

// Round 10
// 221.580 us; speedup vs baseline: 1.1091x; 1.0322x over previous
//
#include <hip/hip_runtime.h>
#include <hip/hip_bf16.h>

#define D_MODEL 1024
#define NUM_HEADS 16
#define HEAD_DIM 64
#define SEQ 2048
#define BATCH 2
#define ROWS (BATCH * SEQ)  // 4096

typedef unsigned short u16;
typedef __bf16 bf16x8 __attribute__((ext_vector_type(8)));
typedef float f32x4 __attribute__((ext_vector_type(4)));

__device__ inline u16 f2bfu(float f) {
  // RNE float->bf16
  unsigned u = __float_as_uint(f);
  unsigned r = (u + 0x7fffu + ((u >> 16) & 1u)) >> 16;
  return (u16)r;
}

// packed f32x2 -> bf16x2 (one v_cvt_pk_bf16_f32 on gfx950; RNE fallback otherwise)
__device__ inline unsigned cvt_pk_bf16(float a, float b) {
#if __has_builtin(__builtin_amdgcn_cvt_pk_bf16_f32)
  auto r = __builtin_amdgcn_cvt_pk_bf16_f32(a, b);
  unsigned u;
  __builtin_memcpy(&u, &r, 4);
  return u;
#else
  return (unsigned)f2bfu(a) | ((unsigned)f2bfu(b) << 16);
#endif
}

__device__ inline f32x4 mfma16(bf16x8 a, bf16x8 b, f32x4 c) {
  return __builtin_amdgcn_mfma_f32_16x16x32_bf16(a, b, c, 0, 0, 0);
}

__device__ inline bf16x8 load_frag(const u16* p) {
  union { uint4 v; bf16x8 f; } u;
  u.v = *(const uint4*)p;
  return u.f;
}

// async global->LDS, 16B per lane; LDS dest = wave-uniform base + lane*16
__device__ inline void gload_lds16(const u16* g, u16* l) {
  __builtin_amdgcn_global_load_lds((const __attribute__((address_space(1))) void*)g,
                                   (__attribute__((address_space(3))) void*)l, 16, 0, 0);
}

// ---------------- converters ----------------

__global__ __launch_bounds__(256) void cvt_x_kernel(const float* __restrict__ x,
                                                    u16* __restrict__ y) {
  int i = blockIdx.x * 256 + threadIdx.x;  // each handles 4 floats
  float4 v = ((const float4*)x)[i];
  uint2 o;
  o.x = cvt_pk_bf16(v.x, v.y);
  o.y = cvt_pk_bf16(v.z, v.w);
  ((uint2*)y)[i] = o;
}

// W [K][N] fp32 -> Wt [N][K] bf16
__global__ __launch_bounds__(256) void transpose_cvt(const float* __restrict__ W,
                                                     u16* __restrict__ Wt,
                                                     int K, int N) {
  __shared__ float t[32][33];
  int k0 = blockIdx.x * 32, n0 = blockIdx.y * 32;
  int c = threadIdx.x & 31, r8 = threadIdx.x >> 5;
#pragma unroll
  for (int i = 0; i < 4; i++) {
    int r = r8 + i * 8;
    t[r][c] = W[(size_t)(k0 + r) * N + n0 + c];
  }
  __syncthreads();
#pragma unroll
  for (int i = 0; i < 4; i++) {
    int r = r8 + i * 8;
    Wt[(size_t)(n0 + r) * K + k0 + c] = f2bfu(t[c][r]);
  }
}

// ---------------- GEMM 1: qkv = x @ W_qkv + b -> Qb/Kb [bh][s][64], Vt [bh][d][s] ----------------
// 128x128 tile, BK=32, explicit double buffer with raw s_barrier + s_waitcnt vmcnt(4):
// loads for tile k+1 stay IN FLIGHT across tile k's compute (no vmcnt(0) drain).
// [validated r9: gemm_qkv 86 -> <62 us with this structure]

__global__ __launch_bounds__(256, 3) void gemm_qkv(const u16* __restrict__ A,   // xb [4096][1024]
                                                   const u16* __restrict__ Bt,  // WqkvT [3072][1024]
                                                   const float* __restrict__ bias,
                                                   u16* __restrict__ Qb, u16* __restrict__ Kb,
                                                   u16* __restrict__ Vt) {
  __shared__ u16 lA0[128 * 32], lB0[128 * 32];  // 8 KB each
  __shared__ u16 lA1[128 * 32], lB1[128 * 32];
  const int tid = threadIdx.x;
  const int wave = tid >> 6, lane = tid & 63, ln = lane & 15, quad = lane >> 4;
  const int n0 = blockIdx.x * 128, m0 = blockIdx.y * 128;
  const int wm = (wave & 1) * 64, wn = (wave >> 1) * 64;
  f32x4 acc[4][4] = {};

  auto issue = [&](u16* dA, u16* dB, int k0) {
#pragma unroll
    for (int i = 0; i < 2; ++i) {
      int rb = wave * 2 + i;  // 0..7
      gload_lds16(A + (size_t)(m0 + rb * 16 + ln) * 1024 + k0 + quad * 8, dA + rb * 512);
      gload_lds16(Bt + (size_t)(n0 + rb * 16 + ln) * 1024 + k0 + quad * 8, dB + rb * 512);
    }
  };
  auto compute = [&](const u16* sA, const u16* sB) {
    bf16x8 a[4], b[4];
#pragma unroll
    for (int i = 0; i < 4; ++i) {
      a[i] = load_frag(sA + (wm / 16 + i) * 512 + quad * 128 + ln * 8);
      b[i] = load_frag(sB + (wn / 16 + i) * 512 + quad * 128 + ln * 8);
    }
#pragma unroll
    for (int mt = 0; mt < 4; ++mt)
#pragma unroll
      for (int nt = 0; nt < 4; ++nt) acc[mt][nt] = mfma16(a[mt], b[nt], acc[mt][nt]);
  };

  issue(lA0, lB0, 0);  // prologue: tile 0 -> buf0
  for (int p = 0; p < 15; ++p) {
    asm volatile("s_barrier" ::: "memory");
    issue(lA1, lB1, (2 * p + 1) * 32);
    asm volatile("s_waitcnt vmcnt(4)" ::: "memory");
    asm volatile("s_barrier" ::: "memory");
    compute(lA0, lB0);
    asm volatile("s_barrier" ::: "memory");
    issue(lA0, lB0, (2 * p + 2) * 32);
    asm volatile("s_waitcnt vmcnt(4)" ::: "memory");
    asm volatile("s_barrier" ::: "memory");
    compute(lA1, lB1);
  }
  asm volatile("s_barrier" ::: "memory");
  issue(lA1, lB1, 31 * 32);
  asm volatile("s_waitcnt vmcnt(4)" ::: "memory");
  asm volatile("s_barrier" ::: "memory");
  compute(lA0, lB0);
  asm volatile("s_waitcnt vmcnt(0)" ::: "memory");
  asm volatile("s_barrier" ::: "memory");
  compute(lA1, lB1);

#pragma unroll
  for (int mt = 0; mt < 4; ++mt) {
    int row = m0 + wm + mt * 16 + quad * 4;
    int bb = row >> 11, s0 = row & 2047;
#pragma unroll
    for (int nt = 0; nt < 4; ++nt) {
      int col = n0 + wn + nt * 16 + ln;
      float bv = bias[col];
      int h = col / 192, rem = col - h * 192, t3 = rem >> 6, d = rem & 63;
      int bh = bb * NUM_HEADS + h;
      if (t3 == 2) {  // V -> transposed layout [bh][d][s], 4 consecutive s packed
        uint2 pk;
        pk.x = cvt_pk_bf16(acc[mt][nt][0] + bv, acc[mt][nt][1] + bv);
        pk.y = cvt_pk_bf16(acc[mt][nt][2] + bv, acc[mt][nt][3] + bv);
        *(uint2*)(Vt + ((size_t)bh * 64 + d) * SEQ + s0) = pk;
      } else {
        u16* dst = (t3 == 0) ? Qb : Kb;
#pragma unroll
        for (int r = 0; r < 4; ++r)
          dst[((size_t)bh * SEQ + s0 + r) * 64 + d] = f2bfu(acc[mt][nt][r] + bv);
      }
    }
  }
}

// ---------------- flash attention, balanced-pair blocks + async K/V double-buffer ----------------
// Block j (0..15): q-tiles lo=j, hi=31-j -> 33 key-tiles for every block (perfect balance).
// 8 waves: waves 0-3 own lo rows, 4-7 own hi rows. Per 64-key tile: K (8KB) + Vt (8KB)
// double-buffered via global_load_lds w16 (2 chunks/wave), s_barrier + s_waitcnt vmcnt(2):
// tile kt+1's loads in flight across tile kt's softmax+MFMA.

__global__ __launch_bounds__(512) void attn_kernel(const u16* __restrict__ Qb,
                                                   const u16* __restrict__ Kb,
                                                   const u16* __restrict__ Vt,
                                                   u16* __restrict__ Ob) {
  __shared__ u16 lK0[64 * 64], lV0[64 * 64];  // 8 KB each
  __shared__ u16 lK1[64 * 64], lV1[64 * 64];
  __shared__ u16 lP[8][1152];   // per-wave P swizzle (1024 used) + epilogue (16x72 = 1152)
  const int tid = threadIdx.x;
  const int wave = tid >> 6, lane = tid & 63;
  const int ln = lane & 15, quad = lane >> 4;
  const int j = blockIdx.x;  // 0..15
  const int lo = j, hi = 31 - j;
  const int myt = (wave < 4) ? lo : hi;
  const int q0w = myt * 64 + (wave & 3) * 16;  // this wave's 16-row base
  const int ktend = myt;
  const int bh = blockIdx.y;
  const u16* Qg = Qb + (size_t)bh * SEQ * 64;
  const u16* Kg = Kb + (size_t)bh * SEQ * 64;
  const u16* Vg = Vt + (size_t)bh * 64 * SEQ;
  u16* lPw = lP[wave];

  // Q B-frags, loaded once
  bf16x8 qf[2];
#pragma unroll
  for (int ks = 0; ks < 2; ++ks)
    qf[ks] = load_frag(Qg + (size_t)(q0w + ln) * 64 + ks * 32 + quad * 8);

  // staging: wave w owns chunks c = w*2, w*2+1 (c<8 -> K, else V); dual dest sets
  const u16* sp[2];
  u16 *dpa[2], *dpb[2];
  const int sstride = (wave < 4) ? 64 * 64 : 64;  // K: +64 rows; V: +64 cols
#pragma unroll
  for (int i = 0; i < 2; ++i) {
    int c = wave * 2 + i;
    if (c < 8) {
      int rb = c >> 1, kgh = c & 1;
      sp[i] = Kg + (size_t)(rb * 16 + ln) * 64 + (kgh * 4 + quad) * 8;
      dpa[i] = lK0 + rb * 1024 + kgh * 512;
      dpb[i] = lK1 + rb * 1024 + kgh * 512;
    } else {
      int cc = c - 8, rb = cc >> 1, kgh = cc & 1;
      sp[i] = Vg + (size_t)(rb * 16 + ln) * SEQ + (kgh * 4 + quad) * 8;
      dpa[i] = lV0 + rb * 1024 + kgh * 512;
      dpb[i] = lV1 + rb * 1024 + kgh * 512;
    }
  }

  f32x4 o[4] = {};     // O^T: row d=dt*16+quad*4+r, col q=ln
  float m_r = -1e30f;  // raw-score domain
  float l_r = 0.f;
  const float SC = 0.18033688011112042f;  // log2(e) / sqrt(64)
  const int qq = q0w + ln;

  // prologue: tile 0 -> buf a
  gload_lds16(sp[0], dpa[0]);
  gload_lds16(sp[1], dpa[1]);
  sp[0] += sstride; sp[1] += sstride;

  for (int kt = 0; kt <= hi; ++kt) {
    asm volatile("s_barrier" ::: "memory");  // prev consumers of next-buf done
    if (kt < hi) {
      if (kt & 1) { gload_lds16(sp[0], dpa[0]); gload_lds16(sp[1], dpa[1]); }
      else        { gload_lds16(sp[0], dpb[0]); gload_lds16(sp[1], dpb[1]); }
      sp[0] += sstride; sp[1] += sstride;
      asm volatile("s_waitcnt vmcnt(2)" ::: "memory");  // cur tile's loads landed
    } else {
      asm volatile("s_waitcnt vmcnt(0)" ::: "memory");
    }
    asm volatile("s_barrier" ::: "memory");  // all waves' cur loads landed

    if (kt <= ktend) {
      const u16* cK = (kt & 1) ? lK1 : lK0;
      const u16* cV = (kt & 1) ? lV1 : lV0;
      // S^T tile: 64 keys x 16 q
      f32x4 sc[4] = {};
#pragma unroll
      for (int mt = 0; mt < 4; ++mt) {
#pragma unroll
        for (int ks = 0; ks < 2; ++ks) {
          bf16x8 kf = load_frag(cK + mt * 1024 + (ks * 4 + quad) * 128 + ln * 8);
          sc[mt] = mfma16(kf, qf[ks], sc[mt]);
        }
      }
      // causal mask (raw domain), only on this wave's diagonal tile
      if (kt == ktend) {
#pragma unroll
        for (int mt = 0; mt < 4; ++mt) {
          int key0 = kt * 64 + mt * 16 + quad * 4;
#pragma unroll
          for (int r = 0; r < 4; ++r)
            if (key0 + r > qq) sc[mt][r] = -1e30f;
        }
      }
      // online softmax: 16 in-lane values + butterfly over quads
      float mloc = sc[0][0];
#pragma unroll
      for (int mt = 0; mt < 4; ++mt)
#pragma unroll
        for (int r = 0; r < 4; ++r) mloc = fmaxf(mloc, sc[mt][r]);
      mloc = fmaxf(mloc, __shfl_xor(mloc, 16));
      mloc = fmaxf(mloc, __shfl_xor(mloc, 32));
      float mnew = fmaxf(m_r, mloc);
      float alpha = __builtin_amdgcn_exp2f((m_r - mnew) * SC);
      float nmsc = -mnew * SC;
      float sum = 0.f;
#pragma unroll
      for (int mt = 0; mt < 4; ++mt)
#pragma unroll
        for (int r = 0; r < 4; ++r) {
          float p = __builtin_amdgcn_exp2f(__builtin_fmaf(sc[mt][r], SC, nmsc));
          sc[mt][r] = p;
          sum += p;
        }
      sum += __shfl_xor(sum, 16);
      sum += __shfl_xor(sum, 32);
      l_r = l_r * alpha + sum;
      m_r = mnew;
#pragma unroll
      for (int dt = 0; dt < 4; ++dt) o[dt] *= alpha;

      // P -> per-wave LDS, [q][k] with k-granule XOR swizzle, packed b64 writes
#pragma unroll
      for (int mt = 0; mt < 4; ++mt) {
        uint2 pk;
        pk.x = cvt_pk_bf16(sc[mt][0], sc[mt][1]);
        pk.y = cvt_pk_bf16(sc[mt][2], sc[mt][3]);
        int addr = ln * 64 + (((mt * 2 + (quad >> 1)) ^ (ln & 7)) * 8) + (quad & 1) * 4;
        *(uint2*)(lPw + addr) = pk;
      }
      bf16x8 pf[2];
#pragma unroll
      for (int ks = 0; ks < 2; ++ks)
        pf[ks] = load_frag(lPw + ln * 64 + (((ks * 4 + quad) ^ (ln & 7)) * 8));
      // O^T += V^T · P^T
#pragma unroll
      for (int dt = 0; dt < 4; ++dt) {
#pragma unroll
        for (int ks = 0; ks < 2; ++ks) {
          bf16x8 av = load_frag(cV + dt * 1024 + (ks * 4 + quad) * 128 + ln * 8);
          o[dt] = mfma16(av, pf[ks], o[dt]);
        }
      }
    }
  }

  // epilogue: normalize, transpose O^T -> [q][d] via wave-private LDS, 16B stores
  float inv = 1.f / l_r;
#pragma unroll
  for (int dt = 0; dt < 4; ++dt) {
    uint2 pk;
    pk.x = cvt_pk_bf16(o[dt][0] * inv, o[dt][1] * inv);
    pk.y = cvt_pk_bf16(o[dt][2] * inv, o[dt][3] * inv);
    *(uint2*)(lPw + ln * 72 + dt * 16 + quad * 4) = pk;
  }
  const int b = bh >> 4, h = bh & 15;
#pragma unroll
  for (int i = 0; i < 2; ++i) {
    int c = lane + i * 64;
    int qq2 = c >> 3, dg = c & 7;
    uint4 val = *(const uint4*)(lPw + qq2 * 72 + dg * 8);
    *(uint4*)(Ob + ((size_t)b * SEQ + q0w + qq2) * 1024 + h * 64 + dg * 8) = val;
  }
}

// ---------------- GEMM 2: out = values @ W_out + b (fp32 out) ----------------
// 128(M) x 64(N) tile, BK=32, async double buffer (r9-proven pattern), grid 16x32=512.
// Wave w owns rows w*32..+31, all 64 cols; 3 staging chunks/wave -> vmcnt(3).

__global__ __launch_bounds__(256, 3) void gemm_out(const u16* __restrict__ A,   // Ob [4096][1024]
                                                   const u16* __restrict__ Bt,  // WoutT [1024][1024]
                                                   const float* __restrict__ bias,
                                                   float* __restrict__ out) {
  __shared__ u16 lA0[128 * 32], lB0[64 * 32];
  __shared__ u16 lA1[128 * 32], lB1[64 * 32];
  const int tid = threadIdx.x;
  const int wave = tid >> 6, lane = tid & 63, ln = lane & 15, quad = lane >> 4;
  const int n0 = blockIdx.x * 64, m0 = blockIdx.y * 128;
  f32x4 acc[2][4] = {};

  auto issue = [&](u16* dA, u16* dB, int k0) {
#pragma unroll
    for (int i = 0; i < 3; ++i) {
      int c = wave * 3 + i;  // 12 chunks: 8 A + 4 B
      if (c < 8) {
        gload_lds16(A + (size_t)(m0 + c * 16 + ln) * 1024 + k0 + quad * 8, dA + c * 512);
      } else {
        int cc = c - 8;
        gload_lds16(Bt + (size_t)(n0 + cc * 16 + ln) * 1024 + k0 + quad * 8, dB + cc * 512);
      }
    }
  };
  auto compute = [&](const u16* sA, const u16* sB) {
    bf16x8 a[2], b[4];
#pragma unroll
    for (int i = 0; i < 2; ++i)
      a[i] = load_frag(sA + (wave * 2 + i) * 512 + quad * 128 + ln * 8);
#pragma unroll
    for (int i = 0; i < 4; ++i)
      b[i] = load_frag(sB + i * 512 + quad * 128 + ln * 8);
#pragma unroll
    for (int mt = 0; mt < 2; ++mt)
#pragma unroll
      for (int nt = 0; nt < 4; ++nt) acc[mt][nt] = mfma16(a[mt], b[nt], acc[mt][nt]);
  };

  issue(lA0, lB0, 0);
  for (int p = 0; p < 15; ++p) {
    asm volatile("s_barrier" ::: "memory");
    issue(lA1, lB1, (2 * p + 1) * 32);
    asm volatile("s_waitcnt vmcnt(3)" ::: "memory");
    asm volatile("s_barrier" ::: "memory");
    compute(lA0, lB0);
    asm volatile("s_barrier" ::: "memory");
    issue(lA0, lB0, (2 * p + 2) * 32);
    asm volatile("s_waitcnt vmcnt(3)" ::: "memory");
    asm volatile("s_barrier" ::: "memory");
    compute(lA1, lB1);
  }
  asm volatile("s_barrier" ::: "memory");
  issue(lA1, lB1, 31 * 32);
  asm volatile("s_waitcnt vmcnt(3)" ::: "memory");
  asm volatile("s_barrier" ::: "memory");
  compute(lA0, lB0);
  asm volatile("s_waitcnt vmcnt(0)" ::: "memory");
  asm volatile("s_barrier" ::: "memory");
  compute(lA1, lB1);

#pragma unroll
  for (int mt = 0; mt < 2; ++mt) {
    int row = m0 + wave * 32 + mt * 16 + quad * 4;
#pragma unroll
    for (int nt = 0; nt < 4; ++nt) {
      int col = n0 + nt * 16 + ln;
      float bv = bias[col];
#pragma unroll
      for (int r = 0; r < 4; ++r)
        out[(size_t)(row + r) * 1024 + col] = acc[mt][nt][r] + bv;
    }
  }
}

// ---------------- launcher ----------------

extern "C" void kernel_launch(void* const* d_in, const int* in_sizes, int n_in,
                              void* d_out, int out_size, void* d_ws, size_t ws_size,
                              hipStream_t stream) {
  const float* x = (const float*)d_in[0];
  const float* W_qkv = (const float*)d_in[1];
  const float* b_qkv = (const float*)d_in[2];
  const float* W_out = (const float*)d_in[3];
  const float* b_out = (const float*)d_in[4];
  float* out = (float*)d_out;

  char* ws = (char*)d_ws;
  const size_t SZ_XB = (size_t)ROWS * D_MODEL * 2;            // 8 MiB
  const size_t SZ_WQKVT = (size_t)3 * D_MODEL * D_MODEL * 2;  // 6 MiB
  const size_t SZ_WOUTT = (size_t)D_MODEL * D_MODEL * 2;      // 2 MiB
  const size_t SZ_HEADS = (size_t)BATCH * NUM_HEADS * SEQ * HEAD_DIM * 2;  // 8 MiB
  u16* xb = (u16*)(ws);
  u16* WqkvT = (u16*)(ws + SZ_XB);
  u16* WoutT = (u16*)(ws + SZ_XB + SZ_WQKVT);
  u16* Qb = (u16*)(ws + SZ_XB + SZ_WQKVT + SZ_WOUTT);
  u16* Kb = (u16*)(ws + SZ_XB + SZ_WQKVT + SZ_WOUTT + SZ_HEADS);
  u16* Vt = (u16*)(ws + SZ_XB + SZ_WQKVT + SZ_WOUTT + 2 * SZ_HEADS);
  u16* Ob = (u16*)(ws + SZ_XB + SZ_WQKVT + SZ_WOUTT + 3 * SZ_HEADS);

  cvt_x_kernel<<<dim3(ROWS * D_MODEL / 4 / 256), dim3(256), 0, stream>>>(x, xb);
  transpose_cvt<<<dim3(D_MODEL / 32, 3 * D_MODEL / 32), dim3(256), 0, stream>>>(W_qkv, WqkvT,
                                                                                D_MODEL, 3 * D_MODEL);
  transpose_cvt<<<dim3(D_MODEL / 32, D_MODEL / 32), dim3(256), 0, stream>>>(W_out, WoutT,
                                                                            D_MODEL, D_MODEL);
  gemm_qkv<<<dim3(3 * D_MODEL / 128, ROWS / 128), dim3(256), 0, stream>>>(xb, WqkvT, b_qkv,
                                                                          Qb, Kb, Vt);
  attn_kernel<<<dim3(SEQ / 128, BATCH * NUM_HEADS), dim3(512), 0, stream>>>(Qb, Kb, Vt, Ob);
  gemm_out<<<dim3(D_MODEL / 64, ROWS / 128), dim3(256), 0, stream>>>(Ob, WoutT, b_out, out);
}

// Round 11
// 207.830 us; speedup vs baseline: 1.1824x; 1.0662x over previous
//
#include <hip/hip_runtime.h>
#include <hip/hip_bf16.h>

#define D_MODEL 1024
#define NUM_HEADS 16
#define HEAD_DIM 64
#define SEQ 2048
#define BATCH 2
#define ROWS (BATCH * SEQ)  // 4096

typedef unsigned short u16;
typedef __bf16 bf16x8 __attribute__((ext_vector_type(8)));
typedef float f32x4 __attribute__((ext_vector_type(4)));

__device__ inline u16 f2bfu(float f) {
  // RNE float->bf16
  unsigned u = __float_as_uint(f);
  unsigned r = (u + 0x7fffu + ((u >> 16) & 1u)) >> 16;
  return (u16)r;
}

// packed f32x2 -> bf16x2 (one v_cvt_pk_bf16_f32 on gfx950; RNE fallback otherwise)
__device__ inline unsigned cvt_pk_bf16(float a, float b) {
#if __has_builtin(__builtin_amdgcn_cvt_pk_bf16_f32)
  auto r = __builtin_amdgcn_cvt_pk_bf16_f32(a, b);
  unsigned u;
  __builtin_memcpy(&u, &r, 4);
  return u;
#else
  return (unsigned)f2bfu(a) | ((unsigned)f2bfu(b) << 16);
#endif
}

__device__ inline f32x4 mfma16(bf16x8 a, bf16x8 b, f32x4 c) {
  return __builtin_amdgcn_mfma_f32_16x16x32_bf16(a, b, c, 0, 0, 0);
}

__device__ inline bf16x8 load_frag(const u16* p) {
  union { uint4 v; bf16x8 f; } u;
  u.v = *(const uint4*)p;
  return u.f;
}

// async global->LDS, 16B per lane; LDS dest = wave-uniform base + lane*16
__device__ inline void gload_lds16(const u16* g, u16* l) {
  __builtin_amdgcn_global_load_lds((const __attribute__((address_space(1))) void*)g,
                                   (__attribute__((address_space(3))) void*)l, 16, 0, 0);
}

// ---------------- fused prep: cvt x + transpose-cvt both weight matrices ----------------
// grid: [0,4096) cvt_x chunks; [4096,7168) W_qkv 32x32 tiles; [7168,8192) W_out tiles.

__global__ __launch_bounds__(256) void prep_kernel(const float* __restrict__ x,
                                                   u16* __restrict__ xb,
                                                   const float* __restrict__ Wq,
                                                   u16* __restrict__ WqT,
                                                   const float* __restrict__ Wo,
                                                   u16* __restrict__ WoT) {
  __shared__ float t[32][33];
  const int bid = blockIdx.x;
  if (bid < 4096) {
    int i = bid * 256 + threadIdx.x;  // 4 floats each
    float4 v = ((const float4*)x)[i];
    uint2 o;
    o.x = cvt_pk_bf16(v.x, v.y);
    o.y = cvt_pk_bf16(v.z, v.w);
    ((uint2*)xb)[i] = o;
    return;
  }
  const float* W;
  u16* Wt;
  int N, tIdx;
  if (bid < 4096 + 3072) { W = Wq; Wt = WqT; N = 3072; tIdx = bid - 4096; }
  else                   { W = Wo; Wt = WoT; N = 1024; tIdx = bid - 7168; }
  const int k0 = (tIdx & 31) * 32, n0 = (tIdx >> 5) * 32;
  const int c = threadIdx.x & 31, r8 = threadIdx.x >> 5;
#pragma unroll
  for (int i = 0; i < 4; i++) {
    int r = r8 + i * 8;
    t[r][c] = W[(size_t)(k0 + r) * N + n0 + c];
  }
  __syncthreads();
#pragma unroll
  for (int i = 0; i < 4; i++) {
    int r = r8 + i * 8;
    Wt[(size_t)(n0 + r) * 1024 + k0 + c] = f2bfu(t[c][r]);
  }
}

// ---------------- GEMM 1: qkv = x @ W_qkv + b -> Qb/Kb [bh][s][64], Vt [bh][d][s] ----------------
// 128x128 tile, BK=32, explicit double buffer with raw s_barrier + s_waitcnt vmcnt(4).
// [validated r9: 86 -> <62 us]

__global__ __launch_bounds__(256, 3) void gemm_qkv(const u16* __restrict__ A,   // xb [4096][1024]
                                                   const u16* __restrict__ Bt,  // WqkvT [3072][1024]
                                                   const float* __restrict__ bias,
                                                   u16* __restrict__ Qb, u16* __restrict__ Kb,
                                                   u16* __restrict__ Vt) {
  __shared__ u16 lA0[128 * 32], lB0[128 * 32];  // 8 KB each
  __shared__ u16 lA1[128 * 32], lB1[128 * 32];
  const int tid = threadIdx.x;
  const int wave = tid >> 6, lane = tid & 63, ln = lane & 15, quad = lane >> 4;
  const int n0 = blockIdx.x * 128, m0 = blockIdx.y * 128;
  const int wm = (wave & 1) * 64, wn = (wave >> 1) * 64;
  f32x4 acc[4][4] = {};

  auto issue = [&](u16* dA, u16* dB, int k0) {
#pragma unroll
    for (int i = 0; i < 2; ++i) {
      int rb = wave * 2 + i;  // 0..7
      gload_lds16(A + (size_t)(m0 + rb * 16 + ln) * 1024 + k0 + quad * 8, dA + rb * 512);
      gload_lds16(Bt + (size_t)(n0 + rb * 16 + ln) * 1024 + k0 + quad * 8, dB + rb * 512);
    }
  };
  auto compute = [&](const u16* sA, const u16* sB) {
    bf16x8 a[4], b[4];
#pragma unroll
    for (int i = 0; i < 4; ++i) {
      a[i] = load_frag(sA + (wm / 16 + i) * 512 + quad * 128 + ln * 8);
      b[i] = load_frag(sB + (wn / 16 + i) * 512 + quad * 128 + ln * 8);
    }
#pragma unroll
    for (int mt = 0; mt < 4; ++mt)
#pragma unroll
      for (int nt = 0; nt < 4; ++nt) acc[mt][nt] = mfma16(a[mt], b[nt], acc[mt][nt]);
  };

  issue(lA0, lB0, 0);  // prologue: tile 0 -> buf0
  for (int p = 0; p < 15; ++p) {
    asm volatile("s_barrier" ::: "memory");
    issue(lA1, lB1, (2 * p + 1) * 32);
    asm volatile("s_waitcnt vmcnt(4)" ::: "memory");
    asm volatile("s_barrier" ::: "memory");
    compute(lA0, lB0);
    asm volatile("s_barrier" ::: "memory");
    issue(lA0, lB0, (2 * p + 2) * 32);
    asm volatile("s_waitcnt vmcnt(4)" ::: "memory");
    asm volatile("s_barrier" ::: "memory");
    compute(lA1, lB1);
  }
  asm volatile("s_barrier" ::: "memory");
  issue(lA1, lB1, 31 * 32);
  asm volatile("s_waitcnt vmcnt(4)" ::: "memory");
  asm volatile("s_barrier" ::: "memory");
  compute(lA0, lB0);
  asm volatile("s_waitcnt vmcnt(0)" ::: "memory");
  asm volatile("s_barrier" ::: "memory");
  compute(lA1, lB1);

#pragma unroll
  for (int mt = 0; mt < 4; ++mt) {
    int row = m0 + wm + mt * 16 + quad * 4;
    int bb = row >> 11, s0 = row & 2047;
#pragma unroll
    for (int nt = 0; nt < 4; ++nt) {
      int col = n0 + wn + nt * 16 + ln;
      float bv = bias[col];
      int h = col / 192, rem = col - h * 192, t3 = rem >> 6, d = rem & 63;
      int bh = bb * NUM_HEADS + h;
      if (t3 == 2) {  // V -> transposed layout [bh][d][s], 4 consecutive s packed
        uint2 pk;
        pk.x = cvt_pk_bf16(acc[mt][nt][0] + bv, acc[mt][nt][1] + bv);
        pk.y = cvt_pk_bf16(acc[mt][nt][2] + bv, acc[mt][nt][3] + bv);
        *(uint2*)(Vt + ((size_t)bh * 64 + d) * SEQ + s0) = pk;
      } else {
        u16* dst = (t3 == 0) ? Qb : Kb;
#pragma unroll
        for (int r = 0; r < 4; ++r)
          dst[((size_t)bh * SEQ + s0 + r) * 64 + d] = f2bfu(acc[mt][nt][r] + bv);
      }
    }
  }
}

// ---------------- flash attention, balanced-pair blocks + 128-key super-tiles ----------------
// Block j (0..15): q-tiles lo=j, hi=31-j. 8 waves: 0-3 own lo rows, 4-7 own hi rows.
// Per super-iter: stage TWO 64-key tiles (K 16KB + Vt 16KB, single-buffered,
// global_load_lds w16, 4 chunks/wave), then ONE merged online-softmax update over
// 128 keys (halves softmax passes, barriers, alpha-rescales vs 64-key tiles).
// Phantom tail half is staged in-bounds (kt<=31) and masked to -1e30.

__global__ __launch_bounds__(512) void attn_kernel(const u16* __restrict__ Qb,
                                                   const u16* __restrict__ Kb,
                                                   const u16* __restrict__ Vt,
                                                   u16* __restrict__ Ob) {
  __shared__ u16 lK[2 * 64 * 64];  // two 64-key halves, fragment order (8 KB each)
  __shared__ u16 lV[2 * 64 * 64];
  __shared__ u16 lP[8][1152];      // per-wave P swizzle (1024 used) + epilogue (16x72)
  const int tid = threadIdx.x;
  const int wave = tid >> 6, lane = tid & 63;
  const int ln = lane & 15, quad = lane >> 4;
  const int j = blockIdx.x;  // 0..15 (j=0 heaviest, dispatched first)
  const int lo = j, hi = 31 - j;
  const int myt = (wave < 4) ? lo : hi;
  const int q0w = myt * 64 + (wave & 3) * 16;  // this wave's 16-row base
  const int sD = myt >> 1;                     // this wave's diagonal super-tile
  const int nsup = (hi + 2) >> 1;              // block-wide super-iteration count
  const int bh = blockIdx.y;
  const u16* Qg = Qb + (size_t)bh * SEQ * 64;
  const u16* Kg = Kb + (size_t)bh * SEQ * 64;
  const u16* Vg = Vt + (size_t)bh * 64 * SEQ;
  u16* lPw = lP[wave];

  // Q B-frags, loaded once
  bf16x8 qf[2];
#pragma unroll
  for (int ks = 0; ks < 2; ++ks)
    qf[ks] = load_frag(Qg + (size_t)(q0w + ln) * 64 + ks * 32 + quad * 8);

  // staging: 32 chunks of 1KB (16 K + 16 V), wave w owns c = w*4..w*4+3
  // (waves 0-3 all-K, waves 4-7 all-V -> uniform stride per wave)
  const u16* sp[4];
  u16* dp[4];
  const int sstep = (wave < 4) ? 128 * 64 : 128;  // K: +128 rows; V: +128 cols
#pragma unroll
  for (int i = 0; i < 4; ++i) {
    int c = wave * 4 + i;
    if (c < 16) {
      int half = c >> 3, cc = c & 7, rb = cc >> 1, kgh = cc & 1;
      sp[i] = Kg + (size_t)(half * 64 + rb * 16 + ln) * 64 + (kgh * 4 + quad) * 8;
      dp[i] = lK + half * 4096 + rb * 1024 + kgh * 512;
    } else {
      int c2 = c - 16, half = c2 >> 3, cc = c2 & 7, rb = cc >> 1, kgh = cc & 1;
      sp[i] = Vg + (size_t)(rb * 16 + ln) * SEQ + half * 64 + (kgh * 4 + quad) * 8;
      dp[i] = lV + half * 4096 + rb * 1024 + kgh * 512;
    }
  }

  f32x4 o[4] = {};     // O^T: row d=dt*16+quad*4+r, col q=ln
  float m_r = -1e30f;  // raw-score domain
  float l_r = 0.f;
  const float SC = 0.18033688011112042f;  // log2(e) / sqrt(64)
  const int qq = q0w + ln;

  for (int s = 0; s < nsup; ++s) {
    __syncthreads();  // previous super-tile fully consumed
#pragma unroll
    for (int i = 0; i < 4; ++i) { gload_lds16(sp[i], dp[i]); sp[i] += sstep; }
    __syncthreads();  // staging landed (vmcnt drained by barrier)

    if (s <= sD) {
      // S^T: 128 keys x 16 q
      f32x4 sc[2][4] = {};
#pragma unroll
      for (int h = 0; h < 2; ++h)
#pragma unroll
        for (int mt = 0; mt < 4; ++mt)
#pragma unroll
          for (int ks = 0; ks < 2; ++ks) {
            bf16x8 kf = load_frag(lK + h * 4096 + mt * 1024 + (ks * 4 + quad) * 128 + ln * 8);
            sc[h][mt] = mfma16(kf, qf[ks], sc[h][mt]);
          }
      // causal mask only on this wave's diagonal super-tile (covers phantom half too)
      if (s == sD) {
#pragma unroll
        for (int h = 0; h < 2; ++h)
#pragma unroll
          for (int mt = 0; mt < 4; ++mt) {
            int key0 = (2 * s + h) * 64 + mt * 16 + quad * 4;
#pragma unroll
            for (int r = 0; r < 4; ++r)
              if (key0 + r > qq) sc[h][mt][r] = -1e30f;
          }
      }
      // merged online softmax over 32 in-lane scores + quad butterfly
      float mloc = sc[0][0][0];
#pragma unroll
      for (int h = 0; h < 2; ++h)
#pragma unroll
        for (int mt = 0; mt < 4; ++mt)
#pragma unroll
          for (int r = 0; r < 4; ++r) mloc = fmaxf(mloc, sc[h][mt][r]);
      mloc = fmaxf(mloc, __shfl_xor(mloc, 16));
      mloc = fmaxf(mloc, __shfl_xor(mloc, 32));
      float mnew = fmaxf(m_r, mloc);
      float alpha = __builtin_amdgcn_exp2f((m_r - mnew) * SC);
      float nmsc = -mnew * SC;
      float sum = 0.f;
#pragma unroll
      for (int h = 0; h < 2; ++h)
#pragma unroll
        for (int mt = 0; mt < 4; ++mt)
#pragma unroll
          for (int r = 0; r < 4; ++r) {
            float p = __builtin_amdgcn_exp2f(__builtin_fmaf(sc[h][mt][r], SC, nmsc));
            sc[h][mt][r] = p;
            sum += p;
          }
      sum += __shfl_xor(sum, 16);
      sum += __shfl_xor(sum, 32);
      l_r = l_r * alpha + sum;
      m_r = mnew;
#pragma unroll
      for (int dt = 0; dt < 4; ++dt) o[dt] *= alpha;

      // per half: P -> wave-private swizzled LDS, then O^T += V^T·P^T
#pragma unroll
      for (int h = 0; h < 2; ++h) {
#pragma unroll
        for (int mt = 0; mt < 4; ++mt) {
          uint2 pk;
          pk.x = cvt_pk_bf16(sc[h][mt][0], sc[h][mt][1]);
          pk.y = cvt_pk_bf16(sc[h][mt][2], sc[h][mt][3]);
          int addr = ln * 64 + (((mt * 2 + (quad >> 1)) ^ (ln & 7)) * 8) + (quad & 1) * 4;
          *(uint2*)(lPw + addr) = pk;
        }
        bf16x8 pf[2];
#pragma unroll
        for (int ks = 0; ks < 2; ++ks)
          pf[ks] = load_frag(lPw + ln * 64 + (((ks * 4 + quad) ^ (ln & 7)) * 8));
#pragma unroll
        for (int dt = 0; dt < 4; ++dt)
#pragma unroll
          for (int ks = 0; ks < 2; ++ks) {
            bf16x8 av = load_frag(lV + h * 4096 + dt * 1024 + (ks * 4 + quad) * 128 + ln * 8);
            o[dt] = mfma16(av, pf[ks], o[dt]);
          }
      }
    }
  }

  // epilogue: normalize, transpose O^T -> [q][d] via wave-private LDS, 16B stores
  float inv = 1.f / l_r;
#pragma unroll
  for (int dt = 0; dt < 4; ++dt) {
    uint2 pk;
    pk.x = cvt_pk_bf16(o[dt][0] * inv, o[dt][1] * inv);
    pk.y = cvt_pk_bf16(o[dt][2] * inv, o[dt][3] * inv);
    *(uint2*)(lPw + ln * 72 + dt * 16 + quad * 4) = pk;
  }
  const int b = bh >> 4, h2 = bh & 15;
#pragma unroll
  for (int i = 0; i < 2; ++i) {
    int c = lane + i * 64;
    int qq2 = c >> 3, dg = c & 7;
    uint4 val = *(const uint4*)(lPw + qq2 * 72 + dg * 8);
    *(uint4*)(Ob + ((size_t)b * SEQ + q0w + qq2) * 1024 + h2 * 64 + dg * 8) = val;
  }
}

// ---------------- GEMM 2: out = values @ W_out + b (fp32 out) ----------------
// 128(M) x 64(N) tile, BK=32, async double buffer (r9-proven pattern), grid 16x32=512.

__global__ __launch_bounds__(256, 3) void gemm_out(const u16* __restrict__ A,   // Ob [4096][1024]
                                                   const u16* __restrict__ Bt,  // WoutT [1024][1024]
                                                   const float* __restrict__ bias,
                                                   float* __restrict__ out) {
  __shared__ u16 lA0[128 * 32], lB0[64 * 32];
  __shared__ u16 lA1[128 * 32], lB1[64 * 32];
  const int tid = threadIdx.x;
  const int wave = tid >> 6, lane = tid & 63, ln = lane & 15, quad = lane >> 4;
  const int n0 = blockIdx.x * 64, m0 = blockIdx.y * 128;
  f32x4 acc[2][4] = {};

  auto issue = [&](u16* dA, u16* dB, int k0) {
#pragma unroll
    for (int i = 0; i < 3; ++i) {
      int c = wave * 3 + i;  // 12 chunks: 8 A + 4 B
      if (c < 8) {
        gload_lds16(A + (size_t)(m0 + c * 16 + ln) * 1024 + k0 + quad * 8, dA + c * 512);
      } else {
        int cc = c - 8;
        gload_lds16(Bt + (size_t)(n0 + cc * 16 + ln) * 1024 + k0 + quad * 8, dB + cc * 512);
      }
    }
  };
  auto compute = [&](const u16* sA, const u16* sB) {
    bf16x8 a[2], b[4];
#pragma unroll
    for (int i = 0; i < 2; ++i)
      a[i] = load_frag(sA + (wave * 2 + i) * 512 + quad * 128 + ln * 8);
#pragma unroll
    for (int i = 0; i < 4; ++i)
      b[i] = load_frag(sB + i * 512 + quad * 128 + ln * 8);
#pragma unroll
    for (int mt = 0; mt < 2; ++mt)
#pragma unroll
      for (int nt = 0; nt < 4; ++nt) acc[mt][nt] = mfma16(a[mt], b[nt], acc[mt][nt]);
  };

  issue(lA0, lB0, 0);
  for (int p = 0; p < 15; ++p) {
    asm volatile("s_barrier" ::: "memory");
    issue(lA1, lB1, (2 * p + 1) * 32);
    asm volatile("s_waitcnt vmcnt(3)" ::: "memory");
    asm volatile("s_barrier" ::: "memory");
    compute(lA0, lB0);
    asm volatile("s_barrier" ::: "memory");
    issue(lA0, lB0, (2 * p + 2) * 32);
    asm volatile("s_waitcnt vmcnt(3)" ::: "memory");
    asm volatile("s_barrier" ::: "memory");
    compute(lA1, lB1);
  }
  asm volatile("s_barrier" ::: "memory");
  issue(lA1, lB1, 31 * 32);
  asm volatile("s_waitcnt vmcnt(3)" ::: "memory");
  asm volatile("s_barrier" ::: "memory");
  compute(lA0, lB0);
  asm volatile("s_waitcnt vmcnt(0)" ::: "memory");
  asm volatile("s_barrier" ::: "memory");
  compute(lA1, lB1);

#pragma unroll
  for (int mt = 0; mt < 2; ++mt) {
    int row = m0 + wave * 32 + mt * 16 + quad * 4;
#pragma unroll
    for (int nt = 0; nt < 4; ++nt) {
      int col = n0 + nt * 16 + ln;
      float bv = bias[col];
#pragma unroll
      for (int r = 0; r < 4; ++r)
        out[(size_t)(row + r) * 1024 + col] = acc[mt][nt][r] + bv;
    }
  }
}

// ---------------- launcher ----------------

extern "C" void kernel_launch(void* const* d_in, const int* in_sizes, int n_in,
                              void* d_out, int out_size, void* d_ws, size_t ws_size,
                              hipStream_t stream) {
  const float* x = (const float*)d_in[0];
  const float* W_qkv = (const float*)d_in[1];
  const float* b_qkv = (const float*)d_in[2];
  const float* W_out = (const float*)d_in[3];
  const float* b_out = (const float*)d_in[4];
  float* out = (float*)d_out;

  char* ws = (char*)d_ws;
  const size_t SZ_XB = (size_t)ROWS * D_MODEL * 2;            // 8 MiB
  const size_t SZ_WQKVT = (size_t)3 * D_MODEL * D_MODEL * 2;  // 6 MiB
  const size_t SZ_WOUTT = (size_t)D_MODEL * D_MODEL * 2;      // 2 MiB
  const size_t SZ_HEADS = (size_t)BATCH * NUM_HEADS * SEQ * HEAD_DIM * 2;  // 8 MiB
  u16* xb = (u16*)(ws);
  u16* WqkvT = (u16*)(ws + SZ_XB);
  u16* WoutT = (u16*)(ws + SZ_XB + SZ_WQKVT);
  u16* Qb = (u16*)(ws + SZ_XB + SZ_WQKVT + SZ_WOUTT);
  u16* Kb = (u16*)(ws + SZ_XB + SZ_WQKVT + SZ_WOUTT + SZ_HEADS);
  u16* Vt = (u16*)(ws + SZ_XB + SZ_WQKVT + SZ_WOUTT + 2 * SZ_HEADS);
  u16* Ob = (u16*)(ws + SZ_XB + SZ_WQKVT + SZ_WOUTT + 3 * SZ_HEADS);

  prep_kernel<<<dim3(8192), dim3(256), 0, stream>>>(x, xb, W_qkv, WqkvT, W_out, WoutT);
  gemm_qkv<<<dim3(3 * D_MODEL / 128, ROWS / 128), dim3(256), 0, stream>>>(xb, WqkvT, b_qkv,
                                                                          Qb, Kb, Vt);
  attn_kernel<<<dim3(SEQ / 128, BATCH * NUM_HEADS), dim3(512), 0, stream>>>(Qb, Kb, Vt, Ob);
  gemm_out<<<dim3(D_MODEL / 64, ROWS / 128), dim3(256), 0, stream>>>(Ob, WoutT, b_out, out);
}